// Round 10
// baseline (2916.682 us; speedup 1.0000x reference)
//
#include <hip/hip_runtime.h>
#include <hip/hip_fp16.h>
#include <math.h>
#include <stdint.h>

#define B_     2048
#define ZD_    256
#define H_     1024
#define E_     96
#define V_     512
#define BEATS_ 4
#define TICKS_ 6
#define H3_    3072
#define KXT_   1120            // unified tick A K-dim: 1024 (h) + 96 (x_e)
#define KWI_   1120            // tWi K-dim: 96 (x) + 1024 (beat_emb)
#define W0_    25165824UL      // B*24*V, start of samples section in d_out
#define INV2K_ 4.8828125e-4f   // 1/2048

typedef _Float16 f16x8 __attribute__((ext_vector_type(8)));
typedef float    f32x4 __attribute__((ext_vector_type(4)));

__device__ __forceinline__ float sigmoidf_(float x){ return 1.f/(1.f+expf(-x)); }
__device__ __forceinline__ float seluf_(float x){
    const float a = 1.6732632423543772f, s = 1.0507009873554805f;
    return x > 0.f ? s*x : s*a*expm1f(x);
}

// fragment-major (16 rows x 8 k) layout offset, in elements. KD mult of 8.
__device__ __forceinline__ size_t fragoff(int r, int k, int KD){
    return ((size_t)(r>>4)*(KD>>3) + (k>>3))*128 + (size_t)((r&15)<<3) + (k&7);
}

__device__ __forceinline__ void store_pl(_Float16* __restrict__ hi, _Float16* __restrict__ lo,
                                         size_t off, float x){
    _Float16 h = (_Float16)x;
    hi[off] = h;
    lo[off] = (_Float16)((x - (float)h) * 2048.f);
}

__device__ __forceinline__ void gload16(const void* g, void* l){
    __builtin_amdgcn_global_load_lds(
        (const __attribute__((address_space(1))) uint32_t*)g,
        (__attribute__((address_space(3))) uint32_t*)l,
        16, 0, 0);
}

// XCD-aware flat-block decode: requires gridDim.x % 8 == 0.
__device__ __forceinline__ void xcd_decode(int nby, int& bxx, int& byy){
    const int d  = blockIdx.x;
    const int wg = (d & 7) * ((int)gridDim.x >> 3) + (d >> 3);
    bxx = wg / nby;  byy = wg - bxx*nby;
}

// ---------------------------------------------------------------------------
// fp32 -> (hi,lo) fp16 planes, fragment-major. T=1 transposes src.
// ---------------------------------------------------------------------------
template<int T>
__global__ void cvt_pl(const float* __restrict__ src, int ld,
                       _Float16* __restrict__ hi, _Float16* __restrict__ lo,
                       int NR, int NK){
    const int idx = blockIdx.x*256 + threadIdx.x;
    if (idx >= NR*NK) return;
    const int r = idx / NK, k = idx - r*NK;
    const float x = T ? src[(size_t)k*ld + r] : src[(size_t)r*ld + k];
    store_pl(hi, lo, fragoff(r, k, NK), x);
}

// ---------------------------------------------------------------------------
// MFMA fp16x2-split GEMM, single-buffered 2-barrier K-loop.
// C[M,N] = act( sum_k A[m,k]*B[n,k] + bias[n] ).  Tile BM x BN, BK=32, 4 waves.
// SPLITP: plane-writes -> (Chp,Clp,KC) for n<nsplit else (Dh,Dl,KC2) at n-nsplit.
// CAND: per-row per-32-col-slice argmax candidates -> cand[m][bxx*2+wn].
// ---------------------------------------------------------------------------
template<int BM,int BN,int EPI,int BIAS,int WRITEC,int WRITEP,int SPLITP,int CAND>
__global__ __launch_bounds__(256,2)
void mgemm(const _Float16* __restrict__ Ahp, const _Float16* __restrict__ Alp, int KA,
           const _Float16* __restrict__ Bhp, const _Float16* __restrict__ Blp, int KB, int kb0,
           const float* __restrict__ bias,
           float* __restrict__ C, long ldc,
           _Float16* __restrict__ Chp, _Float16* __restrict__ Clp, int KC,
           _Float16* __restrict__ Dh,  _Float16* __restrict__ Dl,  int nsplit, int KC2,
           float2* __restrict__ cand,
           int nby, int K)
{
    constexpr int FR  = BM/32, FN = BN/32;
    constexpr int ARB = BM/16, BRB = BN/16;
    constexpr int TOT = (BM+BN)/8;
    constexpr int LPW = TOT/4;
    __shared__ __align__(16) _Float16 Asm[2][BM*32];
    __shared__ __align__(16) _Float16 Bsm[2][BN*32];

    const int tid  = threadIdx.x;
    const int lane = tid & 63;
    const int w    = tid >> 6;
    const int wm   = w >> 1, wn = w & 1;
    int bxx, byy;  xcd_decode(nby, bxx, byy);
    const int bm   = byy * BM, bn = bxx * BN;
    const int kgA  = KA >> 3, kgB = KB >> 3;
    const int lro  = ((lane>>4)<<7) + ((lane&15)<<3);

    f32x4 acc0[FR][FN], acc1[FR][FN];
#pragma unroll
    for (int i=0;i<FR;i++)
#pragma unroll
        for (int j=0;j<FN;j++){ acc0[i][j]=(f32x4)0.f; acc1[i][j]=(f32x4)0.f; }

    const int NS = K >> 5;
    for (int s=0; s<NS; ++s){
        const int k0 = s*32;
#pragma unroll
        for (int tt=0; tt<LPW; ++tt){
            const int t = w + tt*4;
            const _Float16* g; _Float16* dst;
            if (t < ARB*2){
                const int p = t/ARB, rb = t%ARB;
                g   = (p ? Alp : Ahp) + ((size_t)((bm>>4)+rb)*kgA + (k0>>3))*128;
                dst = &Asm[p][rb*512];
            } else {
                const int u = t - ARB*2, p = u/BRB, rb = u%BRB;
                g   = (p ? Blp : Bhp) + ((size_t)((bn>>4)+rb)*kgB + ((kb0+k0)>>3))*128;
                dst = &Bsm[p][rb*512];
            }
            gload16(g + lane*8, dst);
        }
        __syncthreads();

        f16x8 ah[FR], al[FR], bh[FN], bl[FN];
#pragma unroll
        for (int fr=0; fr<FR; ++fr){
            ah[fr] = *(const f16x8*)&Asm[0][(wm*FR+fr)*512 + lro];
            al[fr] = *(const f16x8*)&Asm[1][(wm*FR+fr)*512 + lro];
        }
#pragma unroll
        for (int fn=0; fn<FN; ++fn){
            bh[fn] = *(const f16x8*)&Bsm[0][(wn*FN+fn)*512 + lro];
            bl[fn] = *(const f16x8*)&Bsm[1][(wn*FN+fn)*512 + lro];
        }
#pragma unroll
        for (int fr=0; fr<FR; ++fr)
#pragma unroll
        for (int fn=0; fn<FN; ++fn){
            acc0[fr][fn] = __builtin_amdgcn_mfma_f32_16x16x32_f16(ah[fr], bh[fn], acc0[fr][fn],0,0,0);
            acc1[fr][fn] = __builtin_amdgcn_mfma_f32_16x16x32_f16(ah[fr], bl[fn], acc1[fr][fn],0,0,0);
            acc1[fr][fn] = __builtin_amdgcn_mfma_f32_16x16x32_f16(al[fr], bh[fn], acc1[fr][fn],0,0,0);
        }
        __syncthreads();
    }

    const int rq = (lane>>4)<<2;
    const int cn = lane & 15;
#pragma unroll
    for (int fr=0; fr<FR; ++fr){
        const int m0 = bm + wm*(BM/2) + fr*16 + rq;
#pragma unroll
        for (int q=0; q<4; ++q){
            const int m = m0 + q;
            float vbest = -1e30f; int ibest = 0;
#pragma unroll
            for (int fn=0; fn<FN; ++fn){
                const int n = bn + wn*(BN/2) + fn*16 + cn;
                float v = acc0[fr][fn][q] + acc1[fr][fn][q]*INV2K_;
                if constexpr(BIAS) v += bias[n];
                if constexpr(EPI==1) v = seluf_(v);
                else if constexpr(EPI==2) v = fmaxf(v, 0.f);
                if constexpr(WRITEC) C[(size_t)m*ldc + n] = v;
                if constexpr(WRITEP){
                    if constexpr(SPLITP){
                        if (n < nsplit) store_pl(Chp, Clp, fragoff(m, n, KC), v);
                        else            store_pl(Dh,  Dl,  fragoff(m, n-nsplit, KC2), v);
                    } else store_pl(Chp, Clp, fragoff(m, n, KC), v);
                }
                if constexpr(CAND){
                    if (fn == 0 || v > vbest){ vbest = v; ibest = n; }
                }
            }
            if constexpr(CAND){
#pragma unroll
                for (int msk=1; msk<16; msk<<=1){
                    const float ov = __shfl_xor(vbest, msk);
                    const int   oi = __shfl_xor(ibest, msk);
                    if (ov > vbest || (ov == vbest && oi < ibest)){ vbest=ov; ibest=oi; }
                }
                if (cn == 0)
                    cand[(size_t)m*16 + bxx*2 + wn] = make_float2(vbest, (float)ibest);
            }
        }
    }
}

// ---------------------------------------------------------------------------
// Fused GRU GEMM+epilogue, BM=64 x BNJ=64 (A-reuse doubled: 16 j-groups).
// 4 waves; wave w owns j in [jb+w*16, jb+w*16+16) for all 3 gates, all 64 rows.
// A planes: h at k<1024 (+ x_e at k>=1024 when HASX, KD=1120).
// B: Wh planes KD=1024 (s<32); Wi planes KD=1120 cols[0,96) (s>=32).
// hv captured from staged LDS A-tile at K-step jcap (no global h re-read).
// PREVEC: gi = fp32 vector prevv[3072]; else pre planes (Ph,Pl) gate-major KD=3072.
// Grid (H/64=16 jb-groups) x (B/64=32 m-groups) = 512, nby=32.
// ---------------------------------------------------------------------------
template<int PREVEC,int HASX,int WRITECTX>
__global__ __launch_bounds__(256,2)
void gru_gemm(const _Float16* __restrict__ Ahp, const _Float16* __restrict__ Alp, int KD,
              const _Float16* __restrict__ Whh, const _Float16* __restrict__ Whl,
              const _Float16* __restrict__ Wih, const _Float16* __restrict__ Wil,
              const float* __restrict__ prevv,
              const _Float16* __restrict__ Ph, const _Float16* __restrict__ Pl,
              const float* __restrict__ bh,
              _Float16* __restrict__ Nh, _Float16* __restrict__ Nl,
              _Float16* __restrict__ Ch, _Float16* __restrict__ Cl)
{
    __shared__ __align__(16) _Float16 Asm[2][4*512];     // 64 rows x 32 k
    __shared__ __align__(16) _Float16 Bsm[2][12*512];    // 192 rows x 32 k

    const int tid  = threadIdx.x;
    const int lane = tid & 63;
    const int w    = tid >> 6;            // j-quarter
    int bxx, byy;  xcd_decode(32, bxx, byy);
    const int bm   = byy * 64, jb = bxx * 64;
    const int kgA  = KD >> 3;
    const int lro  = ((lane>>4)<<7) + ((lane&15)<<3);
    const int rq   = (lane>>4)<<2;
    const int cn   = lane & 15;
    const int jcap = (jb>>5) + (w>>1);    // K-step holding this wave's j-cols
    const int kk   = ((w&1)<<4) + cn;     // col within that K-step's 32

    f32x4 a0[4][3], a1[4][3];
#pragma unroll
    for (int i=0;i<4;i++)
#pragma unroll
        for (int g=0;g<3;g++){ a0[i][g]=(f32x4)0.f; a1[i][g]=(f32x4)0.f; }
    f32x4 x0v[4], x1v[4];
    if constexpr(HASX){
#pragma unroll
        for (int i=0;i<4;i++){ x0v[i]=(f32x4)0.f; x1v[i]=(f32x4)0.f; }
    }
    float hvc[4][4];
#pragma unroll
    for (int i=0;i<4;i++)
#pragma unroll
        for (int q=0;q<4;q++) hvc[i][q]=0.f;

    const int NS = HASX ? 35 : 32;
    for (int s=0; s<NS; ++s){
#pragma unroll
        for (int tt=0; tt<8; ++tt){       // 32 issues: A 8 (4rb x 2pl) + B 24 (12rb x 2pl)
            const int t = w + tt*4;
            const _Float16* g; _Float16* dst;
            if (t < 8){
                const int p = t>>2, rb = t&3;
                g   = (p ? Alp : Ahp) + ((size_t)((bm>>4)+rb)*kgA + s*4)*128;
                dst = &Asm[p][rb*512];
            } else {
                const int u = t-8, p = u/12, rb = u%12;
                const int gg = rb>>2, jbk = rb&3;
                const size_t row = (size_t)(gg*64 + (jb>>4) + jbk);
                if (HASX==0 || s < 32)
                    g = (p ? Whl : Whh) + (row*128 + s*4)*128;
                else
                    g = (p ? Wil : Wih) + (row*140 + (s-32)*4)*128;
                dst = &Bsm[p][rb*512];
            }
            gload16(g + lane*8, dst);
        }
        __syncthreads();

        f16x8 ah[4], al[4];
#pragma unroll
        for (int fr=0; fr<4; ++fr){
            ah[fr] = *(const f16x8*)&Asm[0][fr*512 + lro];
            al[fr] = *(const f16x8*)&Asm[1][fr*512 + lro];
        }
        if (s == jcap){                   // capture old-h for this wave's j-cols
#pragma unroll
            for (int fr=0; fr<4; ++fr)
#pragma unroll
            for (int q=0; q<4; ++q){
                const int idx = fr*512 + (kk>>3)*128 + (rq+q)*8 + (kk&7);
                hvc[fr][q] = (float)Asm[0][idx] + (float)Asm[1][idx]*INV2K_;
            }
        }
#pragma unroll
        for (int g=0; g<3; ++g){
            const f16x8 bhv = *(const f16x8*)&Bsm[0][(g*4+w)*512 + lro];
            const f16x8 blv = *(const f16x8*)&Bsm[1][(g*4+w)*512 + lro];
            if (HASX==0 || g < 2 || s < 32){
#pragma unroll
                for (int fr=0; fr<4; ++fr){
                    a0[fr][g] = __builtin_amdgcn_mfma_f32_16x16x32_f16(ah[fr], bhv, a0[fr][g],0,0,0);
                    a1[fr][g] = __builtin_amdgcn_mfma_f32_16x16x32_f16(ah[fr], blv, a1[fr][g],0,0,0);
                    a1[fr][g] = __builtin_amdgcn_mfma_f32_16x16x32_f16(al[fr], bhv, a1[fr][g],0,0,0);
                }
            } else if constexpr(HASX){
#pragma unroll
                for (int fr=0; fr<4; ++fr){
                    x0v[fr] = __builtin_amdgcn_mfma_f32_16x16x32_f16(ah[fr], bhv, x0v[fr],0,0,0);
                    x1v[fr] = __builtin_amdgcn_mfma_f32_16x16x32_f16(ah[fr], blv, x1v[fr],0,0,0);
                    x1v[fr] = __builtin_amdgcn_mfma_f32_16x16x32_f16(al[fr], bhv, x1v[fr],0,0,0);
                }
            }
        }
        __syncthreads();
    }

    // ---- GRU epilogue ----
    const int j  = jb + w*16 + cn;
    const float bhr = bh[j], bhz = bh[1024+j], bhn = bh[2048+j];
    float pvr, pvz, pvn;
    if constexpr(PREVEC){ pvr = prevv[j]; pvz = prevv[1024+j]; pvn = prevv[2048+j]; }
#pragma unroll
    for (int fr=0; fr<4; ++fr){
        const int m0 = bm + fr*16 + rq;
#pragma unroll
        for (int q=0; q<4; ++q){
            const int m = m0 + q;
            float pre_r, pre_z, pre_n;
            if constexpr(PREVEC){ pre_r=pvr; pre_z=pvz; pre_n=pvn; }
            else {
                const size_t pb = ((size_t)(m>>4)*384 + (j>>3))*128 + (size_t)((m&15)<<3) + (j&7);
                pre_r = (float)Ph[pb]         + (float)Pl[pb]*INV2K_;
                pre_z = (float)Ph[pb+16384]   + (float)Pl[pb+16384]*INV2K_;
                pre_n = (float)Ph[pb+32768]   + (float)Pl[pb+32768]*INV2K_;
            }
            const float vr  = a0[fr][0][q] + a1[fr][0][q]*INV2K_ + pre_r + bhr;
            const float vz  = a0[fr][1][q] + a1[fr][1][q]*INV2K_ + pre_z + bhz;
            const float hn_ = a0[fr][2][q] + a1[fr][2][q]*INV2K_ + bhn;
            float in_;
            if constexpr(HASX) in_ = x0v[fr][q] + x1v[fr][q]*INV2K_ + pre_n;
            else               in_ = pre_n;
            const float r  = sigmoidf_(vr);
            const float zg = sigmoidf_(vz);
            const float nn = tanhf(in_ + r*hn_);
            const float hnew = (1.f-zg)*nn + zg*hvc[fr][q];
            const size_t off = ((size_t)(m>>4)*kgA + (j>>3))*128 + (size_t)((m&15)<<3) + (j&7);
            store_pl(Nh, Nl, off, hnew);
            if constexpr(WRITECTX) store_pl(Ch, Cl, off, hnew);
        }
    }
}

// ---------------------------------------------------------------------------
__global__ void init_xepl_k(const float* __restrict__ x0,
                            _Float16* __restrict__ xh, _Float16* __restrict__ xl){
    const int idx = blockIdx.x*256 + threadIdx.x;
    if (idx >= B_*E_) return;
    const int r = idx / E_, k = idx - r*E_;
    store_pl(xh, xl, fragoff(r, 1024+k, KXT_), x0[k]);
}

__global__ void init_givec_k(const float* __restrict__ b0, const float* __restrict__ bWi,
                             const float* __restrict__ bbi, float* __restrict__ giv){
    const int j = blockIdx.x*256 + threadIdx.x;       // 3072 exact
    giv[j] = b0[0]*bWi[j] + bbi[j];
}

// one wave per row: reduce 16 slice-candidates (first-index tie-break),
// gather embedding -> x_e region of the dst tick buffer, emit sample.
__global__ void argmax_emb_k(const float2* __restrict__ cand,    // [B][16]
                             const float* __restrict__ emb,
                             _Float16* __restrict__ xh, _Float16* __restrict__ xl,
                             float* __restrict__ samples){       // row stride 24
    const int row  = blockIdx.x*4 + (threadIdx.x >> 6);
    const int lane = threadIdx.x & 63;
    float best = -1e30f; int bi = 0x7fffffff;
    if (lane < 16){
        const float2 c = cand[(size_t)row*16 + lane];
        best = c.x; bi = (int)c.y;
    }
#pragma unroll
    for (int off=8; off; off>>=1){
        const float ov = __shfl_xor(best, off);
        const int   oi = __shfl_xor(bi,  off);
        if (ov > best || (ov == best && oi < bi)){ best = ov; bi = oi; }
    }
    bi = __shfl(bi, 0);
    for (int k=lane; k<E_; k+=64)
        store_pl(xh, xl, fragoff(row, 1024+k, KXT_), emb[(size_t)bi*E_ + k]);
    if (lane == 0) samples[(size_t)row*24] = (float)bi;
}

// ---------------------------------------------------------------------------
extern "C" void kernel_launch(void* const* d_in, const int* in_sizes, int n_in,
                              void* d_out, int out_size, void* d_ws, size_t ws_size,
                              hipStream_t stream)
{
    const float* z    = (const float*)d_in[0];
    const float* emb  = (const float*)d_in[3];
    const float* z2W  = (const float*)d_in[4];
    const float* z2b  = (const float*)d_in[5];
    const float* b0   = (const float*)d_in[6];
    const float* bWi  = (const float*)d_in[7];
    const float* bWh  = (const float*)d_in[8];
    const float* bbi  = (const float*)d_in[9];
    const float* bbh  = (const float*)d_in[10];
    const float* hidW = (const float*)d_in[11];
    const float* hidb = (const float*)d_in[12];
    const float* inW  = (const float*)d_in[13];
    const float* inb  = (const float*)d_in[14];
    const float* x0   = (const float*)d_in[15];
    const float* tWi  = (const float*)d_in[16];
    const float* tWh  = (const float*)d_in[17];
    const float* tbi  = (const float*)d_in[18];
    const float* tbh  = (const float*)d_in[19];
    const float* outW = (const float*)d_in[20];
    const float* outb = (const float*)d_in[21];
    float* out = (float*)d_out;

    // ---- workspace carve ----
    char* p = (char*)d_ws;
    auto alloc_f = [&](size_t n){ float*    r = (float*)p;    p += n*4; return r; };
    auto alloc_h = [&](size_t n){ _Float16* r = (_Float16*)p; p += n*2; return r; };

    float* giv    = alloc_f(4096);
    float* cbias  = alloc_f(2048);                      // [hidb | inb]
    float2* cand  = (float2*)alloc_f((size_t)B_*16*2);  // per-row slice candidates

    _Float16 *preh = alloc_h((size_t)B_*H3_), *prel = alloc_h((size_t)B_*H3_);
    _Float16 *Th[2], *Tl[2];                            // tick planes, KD=1120 (h + x_e)
    for (int c=0;c<2;c++){ Th[c]=alloc_h((size_t)B_*KXT_); Tl[c]=alloc_h((size_t)B_*KXT_); }
    _Float16 *bPh[2], *bPl[2];                          // beat h planes, KD=1024
    for (int c=0;c<2;c++){ bPh[c]=alloc_h((size_t)B_*H_); bPl[c]=alloc_h((size_t)B_*H_); }
    _Float16 *ctxh[BEATS_], *ctxl[BEATS_];
    for (int i=0;i<BEATS_;i++){ ctxh[i]=alloc_h((size_t)B_*H_); ctxl[i]=alloc_h((size_t)B_*H_); }
    _Float16 *beplh = alloc_h((size_t)B_*H_),  *bepll = alloc_h((size_t)B_*H_);
    _Float16 *zh    = alloc_h((size_t)B_*ZD_), *zl    = alloc_h((size_t)B_*ZD_);
    _Float16 *z2Wh  = alloc_h((size_t)H_*ZD_), *z2Wl  = alloc_h((size_t)H_*ZD_);
    _Float16 *bWhh  = alloc_h((size_t)H3_*H_), *bWhl  = alloc_h((size_t)H3_*H_);
    _Float16 *combWh= alloc_h((size_t)2048*H_),*combWl= alloc_h((size_t)2048*H_); // [hidW|inW]
    _Float16 *tWih  = alloc_h((size_t)H3_*KWI_), *tWil = alloc_h((size_t)H3_*KWI_);
    _Float16 *tWhh  = alloc_h((size_t)H3_*H_), *tWhl  = alloc_h((size_t)H3_*H_);
    _Float16 *outWh = alloc_h((size_t)V_*H_),  *outWl = alloc_h((size_t)V_*H_);

    const dim3 blk(256);
    auto G1 = [](long n){ return dim3((unsigned)((n+255)/256)); };
    const size_t rbOff = (size_t)64 * 16384;   // row-1024 offset in KD=1024 planes

    // ---- one-time conversions ----
    cvt_pl<0><<<G1((long)B_*ZD_),  blk,0,stream>>>(z,    ZD_, zh,    zl,    B_,  ZD_);
    cvt_pl<1><<<G1((long)H_*ZD_),  blk,0,stream>>>(z2W,  H_,  z2Wh,  z2Wl,  H_,  ZD_);
    cvt_pl<0><<<G1((long)H3_*H_),  blk,0,stream>>>(bWh,  H_,  bWhh,  bWhl,  H3_, H_);
    cvt_pl<1><<<G1((long)H_*H_),   blk,0,stream>>>(hidW, H_,  combWh,       combWl,       H_, H_);
    cvt_pl<1><<<G1((long)H_*H_),   blk,0,stream>>>(inW,  H_,  combWh+rbOff, combWl+rbOff, H_, H_);
    cvt_pl<0><<<G1((long)H3_*KWI_),blk,0,stream>>>(tWi,  KWI_,tWih,  tWil,  H3_, KWI_);
    cvt_pl<0><<<G1((long)H3_*H_),  blk,0,stream>>>(tWh,  H_,  tWhh,  tWhl,  H3_, H_);
    cvt_pl<1><<<G1((long)H_*V_),   blk,0,stream>>>(outW, V_,  outWh, outWl, V_,  H_);

    init_xepl_k<<<G1((long)B_*E_), blk,0,stream>>>(x0, Th[0], Tl[0]);
    init_givec_k<<<H3_/256, blk,0,stream>>>(b0, bWi, bbi, giv);
    hipMemcpyAsync(cbias,        hidb, 1024*4, hipMemcpyDeviceToDevice, stream);
    hipMemcpyAsync(cbias + 1024, inb,  1024*4, hipMemcpyDeviceToDevice, stream);

    // ---- h_beat = selu(z @ z2W + z2b) -> beat planes bP[0] ----
    // grid = (N/64=16)*(M/128=16) = 256, nby=16
    mgemm<128,64,1,1,0,1,0,0><<<dim3(256), blk,0,stream>>>(
        zh, zl, ZD_, z2Wh, z2Wl, ZD_, 0, z2b, nullptr, 0,
        bPh[0], bPl[0], H_, nullptr, nullptr, 0, 0, nullptr, 16, ZD_);

    // ---- beat GRU: 4 fused steps (grid 16 jb x 32 m = 512, nby=32) ----
    for (int s=0; s<BEATS_; ++s){
        gru_gemm<1,0,1><<<dim3(512), blk,0,stream>>>(
            bPh[s&1], bPl[s&1], H_, bWhh, bWhl, nullptr, nullptr,
            giv, nullptr, nullptr, bbh, bPh[(s+1)&1], bPl[(s+1)&1], ctxh[s], ctxl[s]);
    }

    // ---- beats ----
    for (int i=0; i<BEATS_; ++i){
        // [h_tick | beat_emb] = selu(ctx @ [hidW|inW] + [hidb|inb]) split-write
        // grid = (2048/128=16)*(2048/128=16) = 256, nby=16
        mgemm<128,128,1,1,0,1,1,0><<<dim3(256), blk,0,stream>>>(
            ctxh[i], ctxl[i], H_, combWh, combWl, H_, 0, cbias, nullptr, 0,
            Th[0], Tl[0], KXT_, beplh, bepll, 1024, H_, nullptr, 16, H_);
        // pre = beat_emb @ tWi[:,96:].T + tbi -> fp16x2 planes (gate-major KD=3072)
        // grid = (3072/128=24)*(16) = 384, nby=16
        mgemm<128,128,0,1,0,1,0,0><<<dim3(384), blk,0,stream>>>(
            beplh, bepll, H_, tWih, tWil, KWI_, E_, tbi, nullptr, 0,
            preh, prel, H3_, nullptr, nullptr, 0, 0, nullptr, 16, H_);

        for (int t=0; t<TICKS_; ++t){
            const int col = i*TICKS_ + t;
            const int src = t & 1, dst = (t+1) & 1;
            // fused GRU: gh(K=1024) + gi_x(K=96) + pre-planes + nonlinearity (grid 512)
            gru_gemm<0,1,0><<<dim3(512), blk,0,stream>>>(
                Th[src], Tl[src], KXT_, tWhh, tWhl, tWih, tWil,
                nullptr, preh, prel, tbh, Th[dst], Tl[dst], nullptr, nullptr);
            // logits = relu(h @ outW + outb) -> d_out; + 32-col-slice argmax cands
            // grid = (512/64=8)*(2048/64=32) = 256, nby=32
            mgemm<64,64,2,1,1,0,0,1><<<dim3(256), blk,0,stream>>>(
                Th[dst], Tl[dst], KXT_, outWh, outWl, H_, 0, outb,
                out + (size_t)col*V_, 24*V_, nullptr, nullptr, 0,
                nullptr, nullptr, 0, 0, cand, 32, H_);
            // candidate reduce + emb gather -> x_e region of dst buffer
            argmax_emb_k<<<B_/4, blk,0,stream>>>(cand, emb, Th[dst], Tl[dst],
                                                 out + W0_ + col);
        }
    }
    (void)in_sizes; (void)n_in; (void)out_size; (void)ws_size;
}

// Round 11
// 2634.011 us; speedup vs baseline: 1.1073x; 1.1073x over previous
//
#include <hip/hip_runtime.h>
#include <hip/hip_fp16.h>
#include <math.h>
#include <stdint.h>

#define B_     2048
#define ZD_    256
#define H_     1024
#define E_     96
#define V_     512
#define BEATS_ 4
#define TICKS_ 6
#define H3_    3072
#define KXT_   1120            // 1024 (h) + 96 (x_e) merged K for tick GRU
#define W0_    25165824UL      // B*24*V, start of samples section in d_out
#define INV2K_ 4.8828125e-4f   // 1/2048

typedef _Float16 f16x8 __attribute__((ext_vector_type(8)));
typedef float    f32x4 __attribute__((ext_vector_type(4)));

__device__ __forceinline__ float sigmoidf_(float x){ return 1.f/(1.f+expf(-x)); }
__device__ __forceinline__ float seluf_(float x){
    const float a = 1.6732632423543772f, s = 1.0507009873554805f;
    return x > 0.f ? s*x : s*a*expm1f(x);
}

// fragment-major (16 rows x 8 k) layout offset, in elements. KD mult of 8.
__device__ __forceinline__ size_t fragoff(int r, int k, int KD){
    return ((size_t)(r>>4)*(KD>>3) + (k>>3))*128 + (size_t)((r&15)<<3) + (k&7);
}

__device__ __forceinline__ void store_pl(_Float16* __restrict__ hi, _Float16* __restrict__ lo,
                                         size_t off, float x){
    _Float16 h = (_Float16)x;
    hi[off] = h;
    lo[off] = (_Float16)((x - (float)h) * 2048.f);
}

__device__ __forceinline__ void gload16(const void* g, void* l){
    __builtin_amdgcn_global_load_lds(
        (const __attribute__((address_space(1))) uint32_t*)g,
        (__attribute__((address_space(3))) uint32_t*)l,
        16, 0, 0);
}

// ---------------------------------------------------------------------------
// fp32 -> (hi,lo) fp16 planes, fragment-major. T=1 transposes src.
// ---------------------------------------------------------------------------
template<int T>
__global__ void cvt_pl(const float* __restrict__ src, int ld,
                       _Float16* __restrict__ hi, _Float16* __restrict__ lo,
                       int NR, int NK){
    const int idx = blockIdx.x*256 + threadIdx.x;
    if (idx >= NR*NK) return;
    const int r = idx / NK, k = idx - r*NK;
    const float x = T ? src[(size_t)k*ld + r] : src[(size_t)r*ld + k];
    store_pl(hi, lo, fragoff(r, k, NK), x);
}

// ---------------------------------------------------------------------------
// MFMA fp16x2-split GEMM (round-3 structure): single-buffered 2-barrier loop.
// C[M,N] = act( sum_k A[m,k]*B[n,k] + bias[n] ).  Tile BM x BN, BK=32, 4 waves.
// CAND: per-(row, block, wn) argmax candidate -> packed u64 atomicMax(amax[m]).
//       key = (float_bits(v) << 16) | (511 - n): first-index tie-break exact,
//       valid because v >= 0 after relu (EPI==2).
// ---------------------------------------------------------------------------
template<int BM,int BN,int EPI,int BIAS,int WRITEC,int WRITEP,int CAND>
__global__ __launch_bounds__(256,2)
void mgemm(const _Float16* __restrict__ Ahp, const _Float16* __restrict__ Alp, int KA,
           const _Float16* __restrict__ Bhp, const _Float16* __restrict__ Blp, int KB, int kb0,
           const float* __restrict__ bias,
           float* __restrict__ C, long ldc,
           _Float16* __restrict__ Chp, _Float16* __restrict__ Clp, int KC,
           unsigned long long* __restrict__ amax,
           int K)
{
    constexpr int FR  = BM/32, FN = BN/32;
    constexpr int ARB = BM/16, BRB = BN/16;
    constexpr int TOT = (BM+BN)/8;   // 1KB wave-issues per K-step
    __shared__ __align__(16) _Float16 Asm[2][BM*32];
    __shared__ __align__(16) _Float16 Bsm[2][BN*32];

    const int tid  = threadIdx.x;
    const int lane = tid & 63;
    const int w    = tid >> 6;
    const int wm   = w >> 1, wn = w & 1;
    const int bm   = blockIdx.y * BM, bn = blockIdx.x * BN;
    const int kgA  = KA >> 3, kgB = KB >> 3;
    const int lro  = ((lane>>4)<<7) + ((lane&15)<<3);

    f32x4 acc0[FR][FN], acc1[FR][FN];
#pragma unroll
    for (int i=0;i<FR;i++)
#pragma unroll
        for (int j=0;j<FN;j++){ acc0[i][j]=(f32x4)0.f; acc1[i][j]=(f32x4)0.f; }

    for (int k0 = 0; k0 < K; k0 += 32){
#pragma unroll
        for (int tt = 0; tt < TOT/4; ++tt){
            const int t = w + tt*4;
            const _Float16* g; _Float16* dst;
            if (t < ARB*2){
                const int p = t/ARB, rb = t%ARB;
                g   = (p ? Alp : Ahp) + ((size_t)((bm>>4)+rb)*kgA + (k0>>3))*128;
                dst = &Asm[p][rb*512];
            } else {
                const int u = t - ARB*2;
                const int p = u/BRB, rb = u%BRB;
                g   = (p ? Blp : Bhp) + ((size_t)((bn>>4)+rb)*kgB + ((kb0+k0)>>3))*128;
                dst = &Bsm[p][rb*512];
            }
            gload16(g + lane*8, dst);
        }
        __syncthreads();

        f16x8 ah[FR], al[FR], bh[FN], bl[FN];
#pragma unroll
        for (int fr=0; fr<FR; ++fr){
            ah[fr] = *(const f16x8*)&Asm[0][(wm*FR+fr)*512 + lro];
            al[fr] = *(const f16x8*)&Asm[1][(wm*FR+fr)*512 + lro];
        }
#pragma unroll
        for (int fn=0; fn<FN; ++fn){
            bh[fn] = *(const f16x8*)&Bsm[0][(wn*FN+fn)*512 + lro];
            bl[fn] = *(const f16x8*)&Bsm[1][(wn*FN+fn)*512 + lro];
        }
#pragma unroll
        for (int fr=0; fr<FR; ++fr)
#pragma unroll
        for (int fn=0; fn<FN; ++fn){
            acc0[fr][fn] = __builtin_amdgcn_mfma_f32_16x16x32_f16(ah[fr], bh[fn], acc0[fr][fn],0,0,0);
            acc1[fr][fn] = __builtin_amdgcn_mfma_f32_16x16x32_f16(ah[fr], bl[fn], acc1[fr][fn],0,0,0);
            acc1[fr][fn] = __builtin_amdgcn_mfma_f32_16x16x32_f16(al[fr], bh[fn], acc1[fr][fn],0,0,0);
        }
        __syncthreads();
    }

    const int rq = (lane>>4)<<2;
    const int cn = lane & 15;
#pragma unroll
    for (int fr=0; fr<FR; ++fr){
        const int m0 = bm + wm*(BM/2) + fr*16 + rq;
#pragma unroll
        for (int q=0; q<4; ++q){
            const int m = m0 + q;
            float vbest = -1e30f; int ibest = 0;
#pragma unroll
            for (int fn=0; fn<FN; ++fn){
                const int n = bn + wn*(BN/2) + fn*16 + cn;
                float v = acc0[fr][fn][q] + acc1[fr][fn][q]*INV2K_;
                if constexpr(BIAS) v += bias[n];
                if constexpr(EPI==1) v = seluf_(v);
                else if constexpr(EPI==2) v = fmaxf(v, 0.f);
                if constexpr(WRITEC) C[(size_t)m*ldc + n] = v;
                if constexpr(WRITEP) store_pl(Chp, Clp, fragoff(m, n, KC), v);
                if constexpr(CAND){
                    if (fn == 0 || v > vbest){ vbest = v; ibest = n; }
                }
            }
            if constexpr(CAND){
#pragma unroll
                for (int msk=1; msk<16; msk<<=1){
                    const float ov = __shfl_xor(vbest, msk);
                    const int   oi = __shfl_xor(ibest, msk);
                    if (ov > vbest || (ov == vbest && oi < ibest)){ vbest=ov; ibest=oi; }
                }
                if (cn == 0){
                    const unsigned long long key =
                        ((unsigned long long)__float_as_uint(vbest) << 16) |
                        (unsigned)(511 - ibest);
                    atomicMax(&amax[m], key);
                }
            }
        }
    }
}

// ---------------------------------------------------------------------------
// Fused GRU GEMM+epilogue (round-3 structure). Block: 128 m x 32 j x 3 gates.
// A = h planes (KD = 1024 or 1120 with x_e at k>=1024). Wh planes KD=1024.
// HASX: s>=32 K-steps use Wi planes (KD=1120, cols [0,96)); n-gate x-part in
// separate accumulators. PREVEC: gi precomputed vector prev[3072] (beat);
// else matrix prev[m][3072] (tick).
// ---------------------------------------------------------------------------
template<int PREVEC,int HASX,int WRITECTX>
__global__ __launch_bounds__(256,2)
void gru_gemm(const _Float16* __restrict__ Ahp, const _Float16* __restrict__ Alp, int KD,
              const _Float16* __restrict__ Whh, const _Float16* __restrict__ Whl,
              const _Float16* __restrict__ Wih, const _Float16* __restrict__ Wil,
              const float* __restrict__ prev,
              const float* __restrict__ bh,
              _Float16* __restrict__ Nh, _Float16* __restrict__ Nl,
              _Float16* __restrict__ Ch, _Float16* __restrict__ Cl)
{
    __shared__ __align__(16) _Float16 Asm[2][128*32];
    __shared__ __align__(16) _Float16 Bsm[2][96*32];

    const int tid  = threadIdx.x;
    const int lane = tid & 63;
    const int w    = tid >> 6;
    const int wm   = w >> 1, wn = w & 1;
    const int bm   = blockIdx.y * 128, jb = blockIdx.x * 32;
    const int kgA  = KD >> 3;
    const int lro  = ((lane>>4)<<7) + ((lane&15)<<3);

    f32x4 a0[4][3], a1[4][3];
#pragma unroll
    for (int i=0;i<4;i++)
#pragma unroll
        for (int g=0;g<3;g++){ a0[i][g]=(f32x4)0.f; a1[i][g]=(f32x4)0.f; }
    f32x4 x0v[4], x1v[4];
    if constexpr(HASX){
#pragma unroll
        for (int i=0;i<4;i++){ x0v[i]=(f32x4)0.f; x1v[i]=(f32x4)0.f; }
    }

    const int NS = HASX ? 35 : 32;
    for (int s=0; s<NS; ++s){
#pragma unroll
        for (int tt=0; tt<7; ++tt){
            const int t = w + tt*4;
            const _Float16* g; _Float16* dst;
            if (t < 16){
                const int p = t>>3, rb = t&7;
                g   = (p ? Alp : Ahp) + ((size_t)((bm>>4)+rb)*kgA + s*4)*128;
                dst = &Asm[p][rb*512];
            } else {
                const int u = t-16, p = u/6, rb = u%6;
                const int gg = rb>>1, half = rb&1;
                if (HASX==0 || s < 32)
                    g = (p ? Whl : Whh) + ((size_t)(gg*64 + (jb>>4) + half)*128 + s*4)*128;
                else
                    g = (p ? Wil : Wih) + ((size_t)(gg*64 + (jb>>4) + half)*140 + (s-32)*4)*128;
                dst = &Bsm[p][rb*512];
            }
            gload16(g + lane*8, dst);
        }
        __syncthreads();

        f16x8 ah[4], al[4];
#pragma unroll
        for (int fr=0; fr<4; ++fr){
            ah[fr] = *(const f16x8*)&Asm[0][(wm*4+fr)*512 + lro];
            al[fr] = *(const f16x8*)&Asm[1][(wm*4+fr)*512 + lro];
        }
#pragma unroll
        for (int g=0; g<3; ++g){
            const f16x8 bhv = *(const f16x8*)&Bsm[0][(g*2+wn)*512 + lro];
            const f16x8 blv = *(const f16x8*)&Bsm[1][(g*2+wn)*512 + lro];
            if (HASX==0 || g < 2 || s < 32){
#pragma unroll
                for (int fr=0; fr<4; ++fr){
                    a0[fr][g] = __builtin_amdgcn_mfma_f32_16x16x32_f16(ah[fr], bhv, a0[fr][g],0,0,0);
                    a1[fr][g] = __builtin_amdgcn_mfma_f32_16x16x32_f16(ah[fr], blv, a1[fr][g],0,0,0);
                    a1[fr][g] = __builtin_amdgcn_mfma_f32_16x16x32_f16(al[fr], bhv, a1[fr][g],0,0,0);
                }
            } else if constexpr(HASX){
#pragma unroll
                for (int fr=0; fr<4; ++fr){
                    x0v[fr] = __builtin_amdgcn_mfma_f32_16x16x32_f16(ah[fr], bhv, x0v[fr],0,0,0);
                    x1v[fr] = __builtin_amdgcn_mfma_f32_16x16x32_f16(ah[fr], blv, x1v[fr],0,0,0);
                    x1v[fr] = __builtin_amdgcn_mfma_f32_16x16x32_f16(al[fr], bhv, x1v[fr],0,0,0);
                }
            }
        }
        __syncthreads();
    }

    // ---- GRU epilogue ----
    const int rq = (lane>>4)<<2;
    const int j  = jb + wn*16 + (lane & 15);
    const float bhr = bh[j], bhz = bh[1024+j], bhn = bh[2048+j];
    float pvr, pvz, pvn;
    if constexpr(PREVEC){ pvr = prev[j]; pvz = prev[1024+j]; pvn = prev[2048+j]; }
#pragma unroll
    for (int fr=0; fr<4; ++fr){
        const int m0 = bm + wm*64 + fr*16 + rq;
#pragma unroll
        for (int q=0; q<4; ++q){
            const int m = m0 + q;
            float pre_r, pre_z, pre_n;
            if constexpr(PREVEC){ pre_r=pvr; pre_z=pvz; pre_n=pvn; }
            else {
                const float* pm = prev + (size_t)m*H3_ + j;
                pre_r = pm[0]; pre_z = pm[1024]; pre_n = pm[2048];
            }
            const float vr  = a0[fr][0][q] + a1[fr][0][q]*INV2K_ + pre_r + bhr;
            const float vz  = a0[fr][1][q] + a1[fr][1][q]*INV2K_ + pre_z + bhz;
            const float hn_ = a0[fr][2][q] + a1[fr][2][q]*INV2K_ + bhn;
            float in_;
            if constexpr(HASX) in_ = x0v[fr][q] + x1v[fr][q]*INV2K_ + pre_n;
            else               in_ = pre_n;
            const float r  = sigmoidf_(vr);
            const float zg = sigmoidf_(vz);
            const float nn = tanhf(in_ + r*hn_);
            const size_t off = ((size_t)(m>>4)*kgA + (j>>3))*128 + (size_t)((m&15)<<3) + (j&7);
            const float hv = (float)Ahp[off] + (float)Alp[off]*INV2K_;
            const float hnew = (1.f-zg)*nn + zg*hv;
            store_pl(Nh, Nl, off, hnew);
            if constexpr(WRITECTX) store_pl(Ch, Cl, off, hnew);   // beat: KD==1024
        }
    }
}

// ---------------------------------------------------------------------------
__global__ void init_xepl_k(const float* __restrict__ x0,
                            _Float16* __restrict__ xh, _Float16* __restrict__ xl){
    const int idx = blockIdx.x*256 + threadIdx.x;
    if (idx >= B_*E_) return;
    const int r = idx / E_, k = idx - r*E_;
    store_pl(xh, xl, fragoff(r, 1024+k, KXT_), x0[k]);
}

__global__ void init_givec_k(const float* __restrict__ b0, const float* __restrict__ bWi,
                             const float* __restrict__ bbi, float* __restrict__ giv){
    const int j = blockIdx.x*256 + threadIdx.x;       // 3072 exact
    giv[j] = b0[0]*bWi[j] + bbi[j];
}

// one wave per row: decode the packed argmax winner, gather emb -> x_e planes,
// emit sample.
__global__ void finalize_k(const unsigned long long* __restrict__ amax,
                           const float* __restrict__ emb,
                           _Float16* __restrict__ xh, _Float16* __restrict__ xl,
                           float* __restrict__ samples){       // row stride 24
    const int row  = blockIdx.x*4 + (threadIdx.x >> 6);
    const int lane = threadIdx.x & 63;
    const unsigned long long win = amax[row];      // broadcast load
    const int bi = 511 - (int)(win & 0xffffULL);
    for (int k=lane; k<E_; k+=64)
        store_pl(xh, xl, fragoff(row, 1024+k, KXT_), emb[(size_t)bi*E_ + k]);
    if (lane == 0) samples[(size_t)row*24] = (float)bi;
}

// ---------------------------------------------------------------------------
extern "C" void kernel_launch(void* const* d_in, const int* in_sizes, int n_in,
                              void* d_out, int out_size, void* d_ws, size_t ws_size,
                              hipStream_t stream)
{
    const float* z    = (const float*)d_in[0];
    const float* emb  = (const float*)d_in[3];
    const float* z2W  = (const float*)d_in[4];
    const float* z2b  = (const float*)d_in[5];
    const float* b0   = (const float*)d_in[6];
    const float* bWi  = (const float*)d_in[7];
    const float* bWh  = (const float*)d_in[8];
    const float* bbi  = (const float*)d_in[9];
    const float* bbh  = (const float*)d_in[10];
    const float* hidW = (const float*)d_in[11];
    const float* hidb = (const float*)d_in[12];
    const float* inW  = (const float*)d_in[13];
    const float* inb  = (const float*)d_in[14];
    const float* x0   = (const float*)d_in[15];
    const float* tWi  = (const float*)d_in[16];
    const float* tWh  = (const float*)d_in[17];
    const float* tbi  = (const float*)d_in[18];
    const float* tbh  = (const float*)d_in[19];
    const float* outW = (const float*)d_in[20];
    const float* outb = (const float*)d_in[21];
    float* out = (float*)d_out;

    // ---- workspace carve ----
    char* p = (char*)d_ws;
    auto alloc_f = [&](size_t n){ float*    r = (float*)p;    p += n*4; return r; };
    auto alloc_h = [&](size_t n){ _Float16* r = (_Float16*)p; p += n*2; return r; };

    float* giv    = alloc_f(4096);
    float* ws_pre = alloc_f((size_t)B_*H3_);
    unsigned long long* amax = (unsigned long long*)alloc_f((size_t)24*B_*2); // [24][B] u64

    _Float16 *Th[2], *Tl[2];                    // tick planes, KD=1120 (h + x_e)
    for (int c=0;c<2;c++){ Th[c]=alloc_h((size_t)B_*KXT_); Tl[c]=alloc_h((size_t)B_*KXT_); }
    _Float16 *bPh[2], *bPl[2];                  // beat planes, KD=1024
    for (int c=0;c<2;c++){ bPh[c]=alloc_h((size_t)B_*H_); bPl[c]=alloc_h((size_t)B_*H_); }
    _Float16 *ctxh[BEATS_], *ctxl[BEATS_];
    for (int i=0;i<BEATS_;i++){ ctxh[i]=alloc_h((size_t)B_*H_); ctxl[i]=alloc_h((size_t)B_*H_); }
    _Float16 *beplh = alloc_h((size_t)B_*H_),  *bepll = alloc_h((size_t)B_*H_);
    _Float16 *zh    = alloc_h((size_t)B_*ZD_), *zl    = alloc_h((size_t)B_*ZD_);
    _Float16 *z2Wh  = alloc_h((size_t)H_*ZD_), *z2Wl  = alloc_h((size_t)H_*ZD_);
    _Float16 *bWhh  = alloc_h((size_t)H3_*H_), *bWhl  = alloc_h((size_t)H3_*H_);
    _Float16 *hidWh = alloc_h((size_t)H_*H_),  *hidWl = alloc_h((size_t)H_*H_);
    _Float16 *inWh  = alloc_h((size_t)H_*H_),  *inWl  = alloc_h((size_t)H_*H_);
    _Float16 *tWih  = alloc_h((size_t)H3_*KXT_), *tWil = alloc_h((size_t)H3_*KXT_);
    _Float16 *tWhh  = alloc_h((size_t)H3_*H_), *tWhl  = alloc_h((size_t)H3_*H_);
    _Float16 *outWh = alloc_h((size_t)V_*H_),  *outWl = alloc_h((size_t)V_*H_);

    const dim3 blk(256);
    auto G1 = [](long n){ return dim3((unsigned)((n+255)/256)); };

    // ---- one-time init ----
    hipMemsetAsync(amax, 0, (size_t)24*B_*8, stream);

    cvt_pl<0><<<G1((long)B_*ZD_),  blk,0,stream>>>(z,    ZD_,   zh,    zl,    B_,  ZD_);
    cvt_pl<1><<<G1((long)H_*ZD_),  blk,0,stream>>>(z2W,  H_,    z2Wh,  z2Wl,  H_,  ZD_);
    cvt_pl<0><<<G1((long)H3_*H_),  blk,0,stream>>>(bWh,  H_,    bWhh,  bWhl,  H3_, H_);
    cvt_pl<1><<<G1((long)H_*H_),   blk,0,stream>>>(hidW, H_,    hidWh, hidWl, H_,  H_);
    cvt_pl<1><<<G1((long)H_*H_),   blk,0,stream>>>(inW,  H_,    inWh,  inWl,  H_,  H_);
    cvt_pl<0><<<G1((long)H3_*KXT_),blk,0,stream>>>(tWi,  KXT_,  tWih,  tWil,  H3_, KXT_);
    cvt_pl<0><<<G1((long)H3_*H_),  blk,0,stream>>>(tWh,  H_,    tWhh,  tWhl,  H3_, H_);
    cvt_pl<1><<<G1((long)H_*V_),   blk,0,stream>>>(outW, V_,    outWh, outWl, V_,  H_);

    init_xepl_k<<<G1((long)B_*E_), blk,0,stream>>>(x0, Th[0], Tl[0]);
    init_givec_k<<<H3_/256, blk,0,stream>>>(b0, bWi, bbi, giv);

    // ---- h_beat = selu(z @ z2W + z2b) -> beat planes bP[0] ----
    mgemm<128,64,1,1,0,1,0><<<dim3(H_/64, B_/128), blk,0,stream>>>(
        zh, zl, ZD_, z2Wh, z2Wl, ZD_, 0, z2b, nullptr, 0,
        bPh[0], bPl[0], H_, nullptr, ZD_);

    // ---- beat GRU: 4 fused steps ----
    for (int s=0; s<BEATS_; ++s){
        gru_gemm<1,0,1><<<dim3(H_/32, B_/128), blk,0,stream>>>(
            bPh[s&1], bPl[s&1], H_, bWhh, bWhl, nullptr, nullptr,
            giv, bbh, bPh[(s+1)&1], bPl[(s+1)&1], ctxh[s], ctxl[s]);
    }

    // ---- beats ----
    for (int i=0; i<BEATS_; ++i){
        // h_tick = selu(ctx @ hidW + hidb) -> tick planes T[0] (k<1024)
        mgemm<128,64,1,1,0,1,0><<<dim3(H_/64, B_/128), blk,0,stream>>>(
            ctxh[i], ctxl[i], H_, hidWh, hidWl, H_, 0, hidb, nullptr, 0,
            Th[0], Tl[0], KXT_, nullptr, H_);
        // beat_emb = selu(ctx @ inW + inb)
        mgemm<128,64,1,1,0,1,0><<<dim3(H_/64, B_/128), blk,0,stream>>>(
            ctxh[i], ctxl[i], H_, inWh, inWl, H_, 0, inb, nullptr, 0,
            beplh, bepll, H_, nullptr, H_);
        // pre = beat_emb @ tWi[:,96:].T + tbi  (fp32, gate-major)
        mgemm<128,64,0,1,1,0,0><<<dim3(H3_/64, B_/128), blk,0,stream>>>(
            beplh, bepll, H_, tWih, tWil, KXT_, E_, tbi, ws_pre, H3_,
            nullptr, nullptr, 0, nullptr, H_);

        for (int t=0; t<TICKS_; ++t){
            const int col = i*TICKS_ + t;
            const int c = t & 1;
            // fused GRU: gh(K=1024) + gi_x(K=96) + pre + nonlinearity -> T[c^1]
            gru_gemm<0,1,0><<<dim3(H_/32, B_/128), blk,0,stream>>>(
                Th[c], Tl[c], KXT_, tWhh, tWhl, tWih, tWil,
                ws_pre, tbh, Th[c^1], Tl[c^1], nullptr, nullptr);
            // logits = relu(h @ outW + outb) -> d_out block; + packed atomic argmax
            mgemm<64,64,2,1,1,0,1><<<dim3(V_/64, B_/64), blk,0,stream>>>(
                Th[c^1], Tl[c^1], KXT_, outWh, outWl, H_, 0, outb,
                out + (size_t)col*V_, 24*V_, nullptr, nullptr, 0,
                amax + (size_t)col*B_, H_);
            // decode winner + emb gather -> x_e region of T[c^1]
            finalize_k<<<B_/4, blk,0,stream>>>(amax + (size_t)col*B_, emb,
                                               Th[c^1], Tl[c^1], out + W0_ + col);
        }
    }
    (void)in_sizes; (void)n_in; (void)out_size; (void)ws_size;
}